// Round 8
// baseline (425.354 us; speedup 1.0000x reference)
//
#include <hip/hip_runtime.h>
#include <hip/hip_fp16.h>

#define D 64
#define CH  16384   // edges per block in bin_count / bin_scatter
#define CH4 4096    // edges per block in bucket2

// ---------------- degree ----------------

__global__ void deg_init_k(unsigned int* deg, unsigned int* cursor, int n) {
    int i = blockIdx.x * blockDim.x + threadIdx.x;
    if (i < n) deg[i] = 1u;  // self-loop
    if (i == 0) *cursor = 0u;
}

__global__ void deg_count_k(const int* __restrict__ col, unsigned int* deg, int E) {
    int e = blockIdx.x * blockDim.x + threadIdx.x;
    if (e < E) atomicAdd(&deg[col[e]], 1u);
}

// ---------------- dinv + scan-free CSR segment allocation ----------------
// seg[i] = {start, cnt}; cur[i] = start (working cursor for bucket2).

__global__ void alloc_k(const unsigned int* __restrict__ deg, float* __restrict__ dinv,
                        uint2* __restrict__ seg, unsigned int* __restrict__ cur,
                        unsigned int* cursor, int n) {
    int i = blockIdx.x * blockDim.x + threadIdx.x;
    int lane = threadIdx.x & 63;
    unsigned int dg = (i < n) ? deg[i] : 1u;
    if (i < n) dinv[i] = rsqrtf((float)dg);  // dg >= 1 (self-loop)
    unsigned int cnt = (i < n) ? (dg - 1u) : 0u;  // in-edges only
    unsigned int v = cnt;  // inclusive wave scan
#pragma unroll
    for (int off = 1; off < 64; off <<= 1) {
        unsigned int t = (unsigned int)__shfl_up((int)v, off, 64);
        if (lane >= off) v += t;
    }
    unsigned int base = 0;
    if (lane == 63) base = atomicAdd(cursor, v);
    base = (unsigned int)__shfl((int)base, 63, 64);
    if (i < n) {
        unsigned int start = base + v - cnt;
        seg[i] = make_uint2(start, cnt);
        cur[i] = start;
    }
}

// ---------------- two-level binned edge partition ----------------
// Bin = target-node >> shift (<=256 bins). K1 count, K2 scan, K3 scatter into
// bin-grouped tmp with ~672B contiguous runs per (block,bin) -> full-sector stores.

__global__ __launch_bounds__(256) void bin_count_k(const int* __restrict__ col,
                                                   unsigned int* __restrict__ blk_cnt,
                                                   int E, int shift, int nbin, int nblk) {
    __shared__ unsigned int hist[256];
    int t = threadIdx.x, blk = blockIdx.x;
    hist[t] = 0u;
    __syncthreads();
    int base = blk * CH;
    for (int k = 0; k < CH; k += 256) {
        int e = base + k + t;
        if (e < E) atomicAdd(&hist[col[e] >> shift], 1u);
    }
    __syncthreads();
    if (t < nbin) blk_cnt[(size_t)t * nblk + blk] = hist[t];
}

__global__ __launch_bounds__(256) void bin_scan_k(const unsigned int* __restrict__ blk_cnt,
                                                  unsigned int* __restrict__ blk_base,
                                                  int nbin, int nblk) {
    __shared__ unsigned int s[256];
    int b = threadIdx.x;
    unsigned int tot = 0u;
    if (b < nbin)
        for (int k = 0; k < nblk; ++k) tot += blk_cnt[(size_t)b * nblk + k];
    s[b] = (b < nbin) ? tot : 0u;
    __syncthreads();
    for (int off = 1; off < 256; off <<= 1) {  // inclusive Hillis-Steele
        unsigned int v = (b >= off) ? s[b - off] : 0u;
        __syncthreads();
        s[b] += v;
        __syncthreads();
    }
    unsigned int run = s[b] - tot;  // exclusive base of this bin
    if (b < nbin)
        for (int k = 0; k < nblk; ++k) {
            blk_base[(size_t)b * nblk + k] = run;
            run += blk_cnt[(size_t)b * nblk + k];
        }
}

__global__ __launch_bounds__(256) void bin_scatter_k(const int* __restrict__ row,
                                                     const int* __restrict__ col,
                                                     const unsigned int* __restrict__ blk_base,
                                                     int2* __restrict__ tmp,
                                                     int E, int shift, int nbin, int nblk) {
    __shared__ unsigned int pos[256];
    int t = threadIdx.x, blk = blockIdx.x;
    if (t < nbin) pos[t] = blk_base[(size_t)t * nblk + blk];
    __syncthreads();
    int base = blk * CH;
    for (int k = 0; k < CH; k += 256) {
        int e = base + k + t;
        if (e < E) {
            int i = col[e], j = row[e];
            unsigned int p = atomicAdd(&pos[i >> shift], 1u);
            tmp[p] = make_int2(j, i);
        }
    }
}

// ---------------- final per-node scatter from bin-grouped tmp ----------------
// Block reads a contiguous tmp chunk (targets confined to <=2 bins = ~1KB of cur
// and ~256KB of csr destinations -> L2-hot, sectors fill before eviction).

__global__ __launch_bounds__(256) void bucket2_k(const int2* __restrict__ tmp,
                                                 const float* __restrict__ dinv,
                                                 unsigned int* __restrict__ cur,
                                                 int2* __restrict__ csr, int E) {
    int t = threadIdx.x, blk = blockIdx.x;
    int base = blk * CH4;
    for (int k = 0; k < CH4; k += 256) {
        int e = base + k + t;
        if (e < E) {
            int2 p = tmp[e];
            unsigned int pos = atomicAdd(&cur[p.y], 1u);
            csr[pos] = make_int2(p.x, __float_as_int(dinv[p.x] * dinv[p.y]));
        }
    }
}

// ---------------- fp32 -> fp16 feature conversion ----------------

__global__ void f2h_k(const float* __restrict__ x, __half* __restrict__ xh, int n16) {
    int t = blockIdx.x * blockDim.x + threadIdx.x;  // n*16 threads, 4 floats each
    if (t >= n16) return;
    float4 v = ((const float4*)x)[t];
    __half2* o = (__half2*)(xh + (size_t)t * 4);
    o[0] = __float22half2_rn(make_float2(v.x, v.y));
    o[1] = __float22half2_rn(make_float2(v.z, v.w));
}

// ---------------- helpers ----------------

__device__ __forceinline__ void fma_row8(float acc[8], float wgt, float4 raw) {
    const __half2* q = (const __half2*)&raw;
#pragma unroll
    for (int k = 0; k < 4; ++k) {
        float2 f = __half22float2(q[k]);
        acc[2 * k]     = fmaf(wgt, f.x, acc[2 * k]);
        acc[2 * k + 1] = fmaf(wgt, f.y, acc[2 * k + 1]);
    }
}

// Per-slot edge aggregation, unroll 4: 8-lane group owns node i; 4 independent
// row-gather chains in flight (avg degree 16 -> ~4 main-loop iterations).
__device__ __forceinline__ void aggregate_node(const __half* __restrict__ h_in,
                                               const int2* __restrict__ csr,
                                               uint2 sg, int fb, float acc[8]) {
    float a1[8];
#pragma unroll
    for (int k = 0; k < 8; ++k) { acc[k] = 0.0f; a1[k] = 0.0f; }
    unsigned int e = sg.x, end = sg.x + sg.y;
    for (; e + 4 <= end; e += 4) {
        int2 p0 = csr[e];
        int2 p1 = csr[e + 1];
        int2 p2 = csr[e + 2];
        int2 p3 = csr[e + 3];
        float4 r0 = *(const float4*)(h_in + (size_t)p0.x * D + fb);
        float4 r1 = *(const float4*)(h_in + (size_t)p1.x * D + fb);
        float4 r2 = *(const float4*)(h_in + (size_t)p2.x * D + fb);
        float4 r3 = *(const float4*)(h_in + (size_t)p3.x * D + fb);
        fma_row8(acc, __int_as_float(p0.y), r0);
        fma_row8(a1,  __int_as_float(p1.y), r1);
        fma_row8(acc, __int_as_float(p2.y), r2);
        fma_row8(a1,  __int_as_float(p3.y), r3);
    }
    for (; e < end; ++e) {
        int2 p = csr[e];
        float4 r = *(const float4*)(h_in + (size_t)p.x * D + fb);
        fma_row8(acc, __int_as_float(p.y), r);
    }
#pragma unroll
    for (int k = 0; k < 8; ++k) acc[k] += a1[k];
}

// ---------------- hop 1: wave = 8 nodes, 8 lanes per node ----------------

__global__ __launch_bounds__(256) void hop8s_k(const __half* __restrict__ h_in,
                                               const float* __restrict__ dinv,
                                               const uint2* __restrict__ seg,
                                               const int2* __restrict__ csr,
                                               __half* __restrict__ h_out, int n) {
    int wave = blockIdx.x * 4 + (threadIdx.x >> 6);
    int lane = threadIdx.x & 63;
    int g = lane >> 3;          // node slot 0..7
    int fb = (lane & 7) << 3;   // feature base (8 halves = 16B)
    int i = wave * 8 + g;
    bool valid = (i < n);
    uint2 sg = valid ? seg[i] : make_uint2(0u, 0u);
    float acc[8];
    aggregate_node(h_in, csr, sg, fb, acc);
    if (valid) {
        float di = dinv[i];
        float4 s = *(const float4*)(h_in + (size_t)i * D + fb);
        fma_row8(acc, di * di, s);  // self-loop term
        float4 outv;
        __half2* o = (__half2*)&outv;
        o[0] = __float22half2_rn(make_float2(acc[0], acc[1]));
        o[1] = __float22half2_rn(make_float2(acc[2], acc[3]));
        o[2] = __float22half2_rn(make_float2(acc[4], acc[5]));
        o[3] = __float22half2_rn(make_float2(acc[6], acc[7]));
        *(float4*)(h_out + (size_t)i * D + fb) = outv;
    }
}

// ---------------- hop 2 fused with Linear + bias + ReLU (fp32 math) ----------------

__global__ __launch_bounds__(256) void hop8s_linear_k(const __half* __restrict__ h_in,
                                                      const float* __restrict__ dinv,
                                                      const uint2* __restrict__ seg,
                                                      const int2* __restrict__ csr,
                                                      const float* __restrict__ W,
                                                      const float* __restrict__ b,
                                                      float* __restrict__ out, int n) {
    __shared__ float Wt[D][D + 1];   // Wt[d][o] = W[o][d]; +1 pad -> conflict-free
    __shared__ float sh[4][8][D];    // per-wave: 8 aggregated node rows (fp32)
    int tid = threadIdx.x;
    for (int k = tid; k < D * D; k += 256) Wt[k & 63][k >> 6] = W[k];
    __syncthreads();
    int w = tid >> 6, lane = tid & 63;
    int wave = blockIdx.x * 4 + w;
    int g = lane >> 3;
    int fb = (lane & 7) << 3;
    int i = wave * 8 + g;
    bool valid = (i < n);
    uint2 sg = valid ? seg[i] : make_uint2(0u, 0u);
    float acc[8];
    aggregate_node(h_in, csr, sg, fb, acc);
    if (valid) {
        float di = dinv[i];
        float4 s = *(const float4*)(h_in + (size_t)i * D + fb);
        fma_row8(acc, di * di, s);
        *(float4*)&sh[w][g][fb]     = make_float4(acc[0], acc[1], acc[2], acc[3]);
        *(float4*)&sh[w][g][fb + 4] = make_float4(acc[4], acc[5], acc[6], acc[7]);
    }
    // readers are the SAME wave -> compiler inserts lgkmcnt wait; no barrier needed
    float bias = b[lane];
#pragma unroll 1
    for (int nd = 0; nd < 8; ++nd) {
        int i2 = wave * 8 + nd;       // wave-uniform
        if (i2 >= n) break;
        float o = bias;
#pragma unroll
        for (int d = 0; d < D; ++d) o = fmaf(sh[w][nd][d], Wt[d][lane], o);
        out[(size_t)i2 * D + lane] = fmaxf(o, 0.0f);
    }
}

// ---------------- launch ----------------

extern "C" void kernel_launch(void* const* d_in, const int* in_sizes, int n_in,
                              void* d_out, int out_size, void* d_ws, size_t ws_size,
                              hipStream_t stream) {
    const float* x = (const float*)d_in[0];  // [n, 64]
    const float* W = (const float*)d_in[1];  // [64, 64]
    const float* b = (const float*)d_in[2];  // [64]
    const int*   ei = (const int*)d_in[3];   // [2, E] int32

    const int n = in_sizes[0] / D;
    const int E = in_sizes[3] / 2;
    const int* row = ei;       // sources j
    const int* col = ei + E;   // targets i
    float* out = (float*)d_out;

    // bin geometry: <=256 bins of 2^shift target nodes
    int shift = 0;
    while (((n + (1 << shift) - 1) >> shift) > 256) ++shift;  // n=100k -> shift=9, nbin=196
    const int nbin = (n + (1 << shift) - 1) >> shift;
    const int nblk = (E + CH - 1) / CH;

    // ws (~41 MB): deg | dinv | cur | seg | cursor | blk_cnt | blk_base | csr | xh | tmp
    // h1h ALIASES tmp (tmp dead after bucket2_k; both 12.8 MB).
    char* ws = (char*)d_ws;
    size_t off = 0;
    unsigned int* deg      = (unsigned int*)(ws + off); off += (size_t)n * 4;
    float*        dinv     = (float*)(ws + off);        off += (size_t)n * 4;
    unsigned int* cur      = (unsigned int*)(ws + off); off += (size_t)n * 4;
    uint2*        seg      = (uint2*)(ws + off);        off += (size_t)n * 8;
    unsigned int* cursor   = (unsigned int*)(ws + off); off += 16;
    unsigned int* blk_cnt  = (unsigned int*)(ws + off); off += (size_t)256 * nblk * 4;
    unsigned int* blk_base = (unsigned int*)(ws + off); off += (size_t)256 * nblk * 4;
    int2*         csr      = (int2*)(ws + off);         off += (size_t)E * 8;
    __half*       xh       = (__half*)(ws + off);       off += (size_t)n * D * 2;
    size_t tmpsz = (size_t)E * 8;
    size_t h1sz  = (size_t)n * D * 2;
    int2*         tmp      = (int2*)(ws + off);
    __half*       h1h      = (__half*)(ws + off);       off += (tmpsz > h1sz ? tmpsz : h1sz);

    const int nb = (n + 255) / 256;
    const int eb = (E + 255) / 256;
    const int gb = (n + 31) / 32;     // wave = 8 nodes, block = 32 nodes
    const int cb = (n * 16 + 255) / 256;
    const int k4b = (E + CH4 - 1) / CH4;

    deg_init_k<<<nb, 256, 0, stream>>>(deg, cursor, n);
    deg_count_k<<<eb, 256, 0, stream>>>(col, deg, E);
    alloc_k<<<nb, 256, 0, stream>>>(deg, dinv, seg, cur, cursor, n);

    bin_count_k<<<nblk, 256, 0, stream>>>(col, blk_cnt, E, shift, nbin, nblk);
    bin_scan_k<<<1, 256, 0, stream>>>(blk_cnt, blk_base, nbin, nblk);
    bin_scatter_k<<<nblk, 256, 0, stream>>>(row, col, blk_base, tmp, E, shift, nbin, nblk);
    bucket2_k<<<k4b, 256, 0, stream>>>(tmp, dinv, cur, csr, E);

    f2h_k<<<cb, 256, 0, stream>>>(x, xh, n * 16);

    hop8s_k<<<gb, 256, 0, stream>>>(xh, dinv, seg, csr, h1h, n);   // h1h overwrites tmp (dead)
    hop8s_linear_k<<<gb, 256, 0, stream>>>(h1h, dinv, seg, csr, W, b, out, n);
}

// Round 9
// 414.860 us; speedup vs baseline: 1.0253x; 1.0253x over previous
//
#include <hip/hip_runtime.h>
#include <hip/hip_fp16.h>

#define D 64

// ---------------- degree ----------------

__global__ void deg_init_k(unsigned int* deg, unsigned int* cursor, int n) {
    int i = blockIdx.x * blockDim.x + threadIdx.x;
    if (i < n) deg[i] = 1u;  // self-loop
    if (i == 0) *cursor = 0u;
}

__global__ void deg_count_k(const int* __restrict__ col, unsigned int* deg, int E) {
    int e = blockIdx.x * blockDim.x + threadIdx.x;
    if (e < E) atomicAdd(&deg[col[e]], 1u);
}

// ---------------- dinv + scan-free CSR segment allocation ----------------
// seg[i] = {start, cnt}; cur[i] = start (working cursor for bucket).

__global__ void alloc_k(const unsigned int* __restrict__ deg, float* __restrict__ dinv,
                        uint2* __restrict__ seg, unsigned int* __restrict__ cur,
                        unsigned int* cursor, int n) {
    int i = blockIdx.x * blockDim.x + threadIdx.x;
    int lane = threadIdx.x & 63;
    unsigned int dg = (i < n) ? deg[i] : 1u;
    if (i < n) dinv[i] = rsqrtf((float)dg);  // dg >= 1 (self-loop)
    unsigned int cnt = (i < n) ? (dg - 1u) : 0u;  // in-edges only
    unsigned int v = cnt;  // inclusive wave scan
#pragma unroll
    for (int off = 1; off < 64; off <<= 1) {
        unsigned int t = (unsigned int)__shfl_up((int)v, off, 64);
        if (lane >= off) v += t;
    }
    unsigned int base = 0;
    if (lane == 63) base = atomicAdd(cursor, v);
    base = (unsigned int)__shfl((int)base, 63, 64);
    if (i < n) {
        unsigned int start = base + v - cnt;
        seg[i] = make_uint2(start, cnt);
        cur[i] = start;
    }
}

// ---------------- bucket edges into CSR: one 4B store per edge ----------------
// (weights recomputed in the hops from the L2-resident dinv table; 4B entries
// halve the distinct dirty sectors vs int2 -> less partial-sector writeback)

__global__ void bucket_k(const int* __restrict__ row, const int* __restrict__ col,
                         unsigned int* __restrict__ cur, int* __restrict__ csr, int E) {
    int e = blockIdx.x * blockDim.x + threadIdx.x;
    if (e >= E) return;
    int j = row[e], i = col[e];
    unsigned int pos = atomicAdd(&cur[i], 1u);
    csr[pos] = j;
}

// ---------------- fp32 -> fp16 feature conversion ----------------

__global__ void f2h_k(const float* __restrict__ x, __half* __restrict__ xh, int n16) {
    int t = blockIdx.x * blockDim.x + threadIdx.x;  // n*16 threads, 4 floats each
    if (t >= n16) return;
    float4 v = ((const float4*)x)[t];
    __half2* o = (__half2*)(xh + (size_t)t * 4);
    o[0] = __float22half2_rn(make_float2(v.x, v.y));
    o[1] = __float22half2_rn(make_float2(v.z, v.w));
}

// ---------------- helpers ----------------

__device__ __forceinline__ void fma_row8(float acc[8], float wgt, float4 raw) {
    const __half2* q = (const __half2*)&raw;
#pragma unroll
    for (int k = 0; k < 4; ++k) {
        float2 f = __half22float2(q[k]);
        acc[2 * k]     = fmaf(wgt, f.x, acc[2 * k]);
        acc[2 * k + 1] = fmaf(wgt, f.y, acc[2 * k + 1]);
    }
}

// Per-slot edge aggregation, unroll 4: 8-lane group owns node i; 4 independent
// row-gather chains + 4 independent dinv loads in flight per iteration.
__device__ __forceinline__ void aggregate_node(const __half* __restrict__ h_in,
                                               const float* __restrict__ dinv,
                                               const int* __restrict__ csr,
                                               uint2 sg, int fb, float di, float acc[8]) {
    float a1[8];
#pragma unroll
    for (int k = 0; k < 8; ++k) { acc[k] = 0.0f; a1[k] = 0.0f; }
    unsigned int e = sg.x, end = sg.x + sg.y;
    for (; e + 4 <= end; e += 4) {
        int j0 = csr[e], j1 = csr[e + 1], j2 = csr[e + 2], j3 = csr[e + 3];
        float d0 = dinv[j0], d1 = dinv[j1], d2 = dinv[j2], d3 = dinv[j3];
        float4 r0 = *(const float4*)(h_in + (size_t)j0 * D + fb);
        float4 r1 = *(const float4*)(h_in + (size_t)j1 * D + fb);
        float4 r2 = *(const float4*)(h_in + (size_t)j2 * D + fb);
        float4 r3 = *(const float4*)(h_in + (size_t)j3 * D + fb);
        fma_row8(acc, d0 * di, r0);
        fma_row8(a1,  d1 * di, r1);
        fma_row8(acc, d2 * di, r2);
        fma_row8(a1,  d3 * di, r3);
    }
    for (; e < end; ++e) {
        int j = csr[e];
        float dj = dinv[j];
        float4 r = *(const float4*)(h_in + (size_t)j * D + fb);
        fma_row8(acc, dj * di, r);
    }
#pragma unroll
    for (int k = 0; k < 8; ++k) acc[k] += a1[k];
}

// ---------------- hop 1: wave = 8 nodes, 8 lanes per node ----------------

__global__ __launch_bounds__(256) void hop8s_k(const __half* __restrict__ h_in,
                                               const float* __restrict__ dinv,
                                               const uint2* __restrict__ seg,
                                               const int* __restrict__ csr,
                                               __half* __restrict__ h_out, int n) {
    int wave = blockIdx.x * 4 + (threadIdx.x >> 6);
    int lane = threadIdx.x & 63;
    int g = lane >> 3;          // node slot 0..7
    int fb = (lane & 7) << 3;   // feature base (8 halves = 16B)
    int i = wave * 8 + g;
    bool valid = (i < n);
    uint2 sg = valid ? seg[i] : make_uint2(0u, 0u);
    float di = valid ? dinv[i] : 0.0f;
    float acc[8];
    aggregate_node(h_in, dinv, csr, sg, fb, di, acc);
    if (valid) {
        float4 s = *(const float4*)(h_in + (size_t)i * D + fb);
        fma_row8(acc, di * di, s);  // self-loop term
        float4 outv;
        __half2* o = (__half2*)&outv;
        o[0] = __float22half2_rn(make_float2(acc[0], acc[1]));
        o[1] = __float22half2_rn(make_float2(acc[2], acc[3]));
        o[2] = __float22half2_rn(make_float2(acc[4], acc[5]));
        o[3] = __float22half2_rn(make_float2(acc[6], acc[7]));
        *(float4*)(h_out + (size_t)i * D + fb) = outv;
    }
}

// ---------------- hop 2 fused with Linear + bias + ReLU (fp32 math) ----------------

__global__ __launch_bounds__(256) void hop8s_linear_k(const __half* __restrict__ h_in,
                                                      const float* __restrict__ dinv,
                                                      const uint2* __restrict__ seg,
                                                      const int* __restrict__ csr,
                                                      const float* __restrict__ W,
                                                      const float* __restrict__ b,
                                                      float* __restrict__ out, int n) {
    __shared__ float Wt[D][D + 1];   // Wt[d][o] = W[o][d]; +1 pad -> conflict-free
    __shared__ float sh[4][8][D];    // per-wave: 8 aggregated node rows (fp32)
    int tid = threadIdx.x;
    for (int k = tid; k < D * D; k += 256) Wt[k & 63][k >> 6] = W[k];
    __syncthreads();
    int w = tid >> 6, lane = tid & 63;
    int wave = blockIdx.x * 4 + w;
    int g = lane >> 3;
    int fb = (lane & 7) << 3;
    int i = wave * 8 + g;
    bool valid = (i < n);
    uint2 sg = valid ? seg[i] : make_uint2(0u, 0u);
    float di = valid ? dinv[i] : 0.0f;
    float acc[8];
    aggregate_node(h_in, dinv, csr, sg, fb, di, acc);
    if (valid) {
        float4 s = *(const float4*)(h_in + (size_t)i * D + fb);
        fma_row8(acc, di * di, s);
        *(float4*)&sh[w][g][fb]     = make_float4(acc[0], acc[1], acc[2], acc[3]);
        *(float4*)&sh[w][g][fb + 4] = make_float4(acc[4], acc[5], acc[6], acc[7]);
    }
    // readers are the SAME wave -> compiler inserts lgkmcnt wait; no barrier needed
    float bias = b[lane];
#pragma unroll 1
    for (int nd = 0; nd < 8; ++nd) {
        int i2 = wave * 8 + nd;       // wave-uniform
        if (i2 >= n) break;
        float o = bias;
#pragma unroll
        for (int d = 0; d < D; ++d) o = fmaf(sh[w][nd][d], Wt[d][lane], o);
        out[(size_t)i2 * D + lane] = fmaxf(o, 0.0f);
    }
}

// ---------------- launch ----------------

extern "C" void kernel_launch(void* const* d_in, const int* in_sizes, int n_in,
                              void* d_out, int out_size, void* d_ws, size_t ws_size,
                              hipStream_t stream) {
    const float* x = (const float*)d_in[0];  // [n, 64]
    const float* W = (const float*)d_in[1];  // [64, 64]
    const float* b = (const float*)d_in[2];  // [64]
    const int*   ei = (const int*)d_in[3];   // [2, E] int32

    const int n = in_sizes[0] / D;
    const int E = in_sizes[3] / 2;
    const int* row = ei;       // sources j
    const int* col = ei + E;   // targets i
    float* out = (float*)d_out;

    // ws (~34 MB): deg | dinv | cur | seg | cursor | csr(i32) | xh | h1h
    char* ws = (char*)d_ws;
    size_t off = 0;
    unsigned int* deg    = (unsigned int*)(ws + off); off += (size_t)n * 4;
    float*        dinv   = (float*)(ws + off);        off += (size_t)n * 4;
    unsigned int* cur    = (unsigned int*)(ws + off); off += (size_t)n * 4;
    uint2*        seg    = (uint2*)(ws + off);        off += (size_t)n * 8;
    unsigned int* cursor = (unsigned int*)(ws + off); off += 16;
    int*          csr    = (int*)(ws + off);          off += (size_t)E * 4;
    __half*       xh     = (__half*)(ws + off);       off += (size_t)n * D * 2;
    __half*       h1h    = (__half*)(ws + off);       off += (size_t)n * D * 2;

    const int nb = (n + 255) / 256;
    const int eb = (E + 255) / 256;
    const int gb = (n + 31) / 32;     // wave = 8 nodes, block = 32 nodes
    const int cb = (n * 16 + 255) / 256;

    deg_init_k<<<nb, 256, 0, stream>>>(deg, cursor, n);
    deg_count_k<<<eb, 256, 0, stream>>>(col, deg, E);
    alloc_k<<<nb, 256, 0, stream>>>(deg, dinv, seg, cur, cursor, n);
    bucket_k<<<eb, 256, 0, stream>>>(row, col, cur, csr, E);
    f2h_k<<<cb, 256, 0, stream>>>(x, xh, n * 16);

    hop8s_k<<<gb, 256, 0, stream>>>(xh, dinv, seg, csr, h1h, n);
    hop8s_linear_k<<<gb, 256, 0, stream>>>(h1h, dinv, seg, csr, W, b, out, n);
}

// Round 10
// 333.139 us; speedup vs baseline: 1.2768x; 1.2453x over previous
//
#include <hip/hip_runtime.h>
#include <hip/hip_fp16.h>

#define D 64

// ---------------- degree + rank ----------------

__global__ void deg_init_k(unsigned int* deg, unsigned int* cursor, int n) {
    int i = blockIdx.x * blockDim.x + threadIdx.x;
    if (i < n) deg[i] = 0u;  // in-degree only; self-loop added in alloc
    if (i == 0) *cursor = 0u;
}

// rank[e] = this edge's arrival index at its target -> later a unique CSR slot.
__global__ void deg_rank_k(const int* __restrict__ col, unsigned int* deg,
                           unsigned int* __restrict__ rank, int E) {
    int e = blockIdx.x * blockDim.x + threadIdx.x;
    if (e < E) rank[e] = atomicAdd(&deg[col[e]], 1u);
}

// ---------------- dinv + scan-free CSR segment allocation ----------------
// seg[i] = {start, cnt} for hops; start_p[i] = start (4B table for bucket gather).

__global__ void alloc_k(const unsigned int* __restrict__ deg, float* __restrict__ dinv,
                        uint2* __restrict__ seg, unsigned int* __restrict__ start_p,
                        unsigned int* cursor, int n) {
    int i = blockIdx.x * blockDim.x + threadIdx.x;
    int lane = threadIdx.x & 63;
    unsigned int cnt = (i < n) ? deg[i] : 0u;          // in-edges
    if (i < n) dinv[i] = rsqrtf((float)(cnt + 1u));    // +1 self-loop
    unsigned int v = cnt;  // inclusive wave scan
#pragma unroll
    for (int off = 1; off < 64; off <<= 1) {
        unsigned int t = (unsigned int)__shfl_up((int)v, off, 64);
        if (lane >= off) v += t;
    }
    unsigned int base = 0;
    if (lane == 63) base = atomicAdd(cursor, v);
    base = (unsigned int)__shfl((int)base, 63, 64);
    if (i < n) {
        unsigned int start = base + v - cnt;
        seg[i] = make_uint2(start, cnt);
        start_p[i] = start;
    }
}

// ---------------- bucket edges into CSR: NO atomics ----------------
// pos = start[i] + rank[e] is unique; chain is gather(hot 4B) -> store(8B).

__global__ void bucket_k(const int* __restrict__ row, const int* __restrict__ col,
                         const unsigned int* __restrict__ rank,
                         const unsigned int* __restrict__ start_p,
                         const float* __restrict__ dinv,
                         int2* __restrict__ csr, int E) {
    int e = blockIdx.x * blockDim.x + threadIdx.x;
    if (e >= E) return;
    int j = row[e], i = col[e];
    unsigned int pos = start_p[i] + rank[e];
    csr[pos] = make_int2(j, __float_as_int(dinv[j] * dinv[i]));
}

// ---------------- fp32 -> fp16 feature conversion ----------------

__global__ void f2h_k(const float* __restrict__ x, __half* __restrict__ xh, int n16) {
    int t = blockIdx.x * blockDim.x + threadIdx.x;  // n*16 threads, 4 floats each
    if (t >= n16) return;
    float4 v = ((const float4*)x)[t];
    __half2* o = (__half2*)(xh + (size_t)t * 4);
    o[0] = __float22half2_rn(make_float2(v.x, v.y));
    o[1] = __float22half2_rn(make_float2(v.z, v.w));
}

// ---------------- helpers ----------------

__device__ __forceinline__ void fma_row8(float acc[8], float wgt, float4 raw) {
    const __half2* q = (const __half2*)&raw;
#pragma unroll
    for (int k = 0; k < 4; ++k) {
        float2 f = __half22float2(q[k]);
        acc[2 * k]     = fmaf(wgt, f.x, acc[2 * k]);
        acc[2 * k + 1] = fmaf(wgt, f.y, acc[2 * k + 1]);
    }
}

// Per-slot edge aggregation, unroll 4 (round-8 measured-best form):
// 8-lane group owns node i; 4 independent row-gather chains in flight.
__device__ __forceinline__ void aggregate_node(const __half* __restrict__ h_in,
                                               const int2* __restrict__ csr,
                                               uint2 sg, int fb, float acc[8]) {
    float a1[8];
#pragma unroll
    for (int k = 0; k < 8; ++k) { acc[k] = 0.0f; a1[k] = 0.0f; }
    unsigned int e = sg.x, end = sg.x + sg.y;
    for (; e + 4 <= end; e += 4) {
        int2 p0 = csr[e];
        int2 p1 = csr[e + 1];
        int2 p2 = csr[e + 2];
        int2 p3 = csr[e + 3];
        float4 r0 = *(const float4*)(h_in + (size_t)p0.x * D + fb);
        float4 r1 = *(const float4*)(h_in + (size_t)p1.x * D + fb);
        float4 r2 = *(const float4*)(h_in + (size_t)p2.x * D + fb);
        float4 r3 = *(const float4*)(h_in + (size_t)p3.x * D + fb);
        fma_row8(acc, __int_as_float(p0.y), r0);
        fma_row8(a1,  __int_as_float(p1.y), r1);
        fma_row8(acc, __int_as_float(p2.y), r2);
        fma_row8(a1,  __int_as_float(p3.y), r3);
    }
    for (; e < end; ++e) {
        int2 p = csr[e];
        float4 r = *(const float4*)(h_in + (size_t)p.x * D + fb);
        fma_row8(acc, __int_as_float(p.y), r);
    }
#pragma unroll
    for (int k = 0; k < 8; ++k) acc[k] += a1[k];
}

// ---------------- hop 1: wave = 8 nodes, 8 lanes per node ----------------

__global__ __launch_bounds__(256) void hop8s_k(const __half* __restrict__ h_in,
                                               const float* __restrict__ dinv,
                                               const uint2* __restrict__ seg,
                                               const int2* __restrict__ csr,
                                               __half* __restrict__ h_out, int n) {
    int wave = blockIdx.x * 4 + (threadIdx.x >> 6);
    int lane = threadIdx.x & 63;
    int g = lane >> 3;          // node slot 0..7
    int fb = (lane & 7) << 3;   // feature base (8 halves = 16B)
    int i = wave * 8 + g;
    bool valid = (i < n);
    uint2 sg = valid ? seg[i] : make_uint2(0u, 0u);
    float acc[8];
    aggregate_node(h_in, csr, sg, fb, acc);
    if (valid) {
        float di = dinv[i];
        float4 s = *(const float4*)(h_in + (size_t)i * D + fb);
        fma_row8(acc, di * di, s);  // self-loop term
        float4 outv;
        __half2* o = (__half2*)&outv;
        o[0] = __float22half2_rn(make_float2(acc[0], acc[1]));
        o[1] = __float22half2_rn(make_float2(acc[2], acc[3]));
        o[2] = __float22half2_rn(make_float2(acc[4], acc[5]));
        o[3] = __float22half2_rn(make_float2(acc[6], acc[7]));
        *(float4*)(h_out + (size_t)i * D + fb) = outv;
    }
}

// ---------------- hop 2 fused with Linear + bias + ReLU (fp32 math) ----------------

__global__ __launch_bounds__(256) void hop8s_linear_k(const __half* __restrict__ h_in,
                                                      const float* __restrict__ dinv,
                                                      const uint2* __restrict__ seg,
                                                      const int2* __restrict__ csr,
                                                      const float* __restrict__ W,
                                                      const float* __restrict__ b,
                                                      float* __restrict__ out, int n) {
    __shared__ float Wt[D][D + 1];   // Wt[d][o] = W[o][d]; +1 pad -> conflict-free
    __shared__ float sh[4][8][D];    // per-wave: 8 aggregated node rows (fp32)
    int tid = threadIdx.x;
    for (int k = tid; k < D * D; k += 256) Wt[k & 63][k >> 6] = W[k];
    __syncthreads();
    int w = tid >> 6, lane = tid & 63;
    int wave = blockIdx.x * 4 + w;
    int g = lane >> 3;
    int fb = (lane & 7) << 3;
    int i = wave * 8 + g;
    bool valid = (i < n);
    uint2 sg = valid ? seg[i] : make_uint2(0u, 0u);
    float acc[8];
    aggregate_node(h_in, csr, sg, fb, acc);
    if (valid) {
        float di = dinv[i];
        float4 s = *(const float4*)(h_in + (size_t)i * D + fb);
        fma_row8(acc, di * di, s);
        *(float4*)&sh[w][g][fb]     = make_float4(acc[0], acc[1], acc[2], acc[3]);
        *(float4*)&sh[w][g][fb + 4] = make_float4(acc[4], acc[5], acc[6], acc[7]);
    }
    // readers are the SAME wave -> compiler inserts lgkmcnt wait; no barrier needed
    float bias = b[lane];
#pragma unroll 1
    for (int nd = 0; nd < 8; ++nd) {
        int i2 = wave * 8 + nd;       // wave-uniform
        if (i2 >= n) break;
        float o = bias;
#pragma unroll
        for (int d = 0; d < D; ++d) o = fmaf(sh[w][nd][d], Wt[d][lane], o);
        out[(size_t)i2 * D + lane] = fmaxf(o, 0.0f);
    }
}

// ---------------- launch ----------------

extern "C" void kernel_launch(void* const* d_in, const int* in_sizes, int n_in,
                              void* d_out, int out_size, void* d_ws, size_t ws_size,
                              hipStream_t stream) {
    const float* x = (const float*)d_in[0];  // [n, 64]
    const float* W = (const float*)d_in[1];  // [64, 64]
    const float* b = (const float*)d_in[2];  // [64]
    const int*   ei = (const int*)d_in[3];   // [2, E] int32

    const int n = in_sizes[0] / D;
    const int E = in_sizes[3] / 2;
    const int* row = ei;       // sources j
    const int* col = ei + E;   // targets i
    float* out = (float*)d_out;

    // ws (~47 MB): deg | dinv | start_p | seg | cursor | rank | csr(int2) | xh | h1h
    char* ws = (char*)d_ws;
    size_t off = 0;
    unsigned int* deg     = (unsigned int*)(ws + off); off += (size_t)n * 4;
    float*        dinv    = (float*)(ws + off);        off += (size_t)n * 4;
    unsigned int* start_p = (unsigned int*)(ws + off); off += (size_t)n * 4;
    uint2*        seg     = (uint2*)(ws + off);        off += (size_t)n * 8;
    unsigned int* cursor  = (unsigned int*)(ws + off); off += 16;
    unsigned int* rank    = (unsigned int*)(ws + off); off += (size_t)E * 4;
    int2*         csr     = (int2*)(ws + off);         off += (size_t)E * 8;
    __half*       xh      = (__half*)(ws + off);       off += (size_t)n * D * 2;
    __half*       h1h     = (__half*)(ws + off);       off += (size_t)n * D * 2;

    const int nb = (n + 255) / 256;
    const int eb = (E + 255) / 256;
    const int gb = (n + 31) / 32;     // wave = 8 nodes, block = 32 nodes
    const int cb = (n * 16 + 255) / 256;

    deg_init_k<<<nb, 256, 0, stream>>>(deg, cursor, n);
    deg_rank_k<<<eb, 256, 0, stream>>>(col, deg, rank, E);
    alloc_k<<<nb, 256, 0, stream>>>(deg, dinv, seg, start_p, cursor, n);
    bucket_k<<<eb, 256, 0, stream>>>(row, col, rank, start_p, dinv, csr, E);
    f2h_k<<<cb, 256, 0, stream>>>(x, xh, n * 16);

    hop8s_k<<<gb, 256, 0, stream>>>(xh, dinv, seg, csr, h1h, n);
    hop8s_linear_k<<<gb, 256, 0, stream>>>(h1h, dinv, seg, csr, W, b, out, n);
}